// Round 1
// baseline (146.108 us; speedup 1.0000x reference)
//
#include <hip/hip_runtime.h>
#include <hip/hip_bf16.h>

#define B_    128
#define N_    4096
#define DIM_  16
#define HID_  128
#define ROWS_ 512           // n-rows per block
#define CHUNK_ 128          // rows per inner chunk
#define NCH_  (ROWS_ / CHUNK_)

typedef __bf16 bf16x8 __attribute__((ext_vector_type(8)));
typedef float floatx16 __attribute__((ext_vector_type(16)));

__device__ inline bf16x8 load_cvt8(const float* __restrict__ p) {
  const float4 u = *(const float4*)p;
  const float4 v = *(const float4*)(p + 4);
  bf16x8 r;
  r[0] = (__bf16)u.x; r[1] = (__bf16)u.y; r[2] = (__bf16)u.z; r[3] = (__bf16)u.w;
  r[4] = (__bf16)v.x; r[5] = (__bf16)v.y; r[6] = (__bf16)v.z; r[7] = (__bf16)v.w;
  return r;
}

// h1 = relu([x | ender] @ W_n2e + b_n2e); h2 = relu(h1 @ W_e2e + b_e2e);
// acc[b,:] += sum_n mask[n] * h2[b,n,:]
__global__ __launch_bounds__(256, 2) void edge_kernel(
    const float* __restrict__ x, const float* __restrict__ adj,
    const float* __restrict__ W1, const float* __restrict__ b1,
    const float* __restrict__ W2, const float* __restrict__ b2,
    const int* __restrict__ ip, float* __restrict__ accg)
{
  // transposed weight tiles: s*T[n][k]; strides multiple of 8 for 16B-aligned reads
  __shared__ __align__(16) __bf16 sW1T[HID_][24];     // k < 16 (starter half only)
  __shared__ __align__(16) __bf16 sW2T[HID_][136];
  __shared__ __align__(16) __bf16 sH1[CHUNK_][136];
  __shared__ float sB1[HID_], sB2[HID_], sAcc[HID_], sEnder[DIM_];

  const int t  = threadIdx.x;
  const int b  = blockIdx.y;
  const int n0 = blockIdx.x * ROWS_;
  const int ii = __ldg(ip);

  if (t < DIM_) sEnder[t] = x[((size_t)b * N_ + ii) * DIM_ + t];
  for (int e = t; e < DIM_ * HID_; e += 256) {         // W1[0:16,:] transposed
    int k = e >> 7, n = e & 127;
    sW1T[n][k] = (__bf16)W1[k * HID_ + n];
  }
  for (int e = t; e < HID_ * HID_; e += 256) {         // W2 transposed
    int k = e >> 7, n = e & 127;
    sW2T[n][k] = (__bf16)W2[k * HID_ + n];
  }
  __syncthreads();
  if (t < HID_) {
    // fold ender @ W1[16:32,:] into the stage-A bias (fp32, exact-ish)
    float s = b1[t];
    #pragma unroll
    for (int k = 0; k < DIM_; ++k) s += sEnder[k] * W1[(DIM_ + k) * HID_ + t];
    sB1[t] = s;
    sB2[t] = b2[t];
    sAcc[t] = 0.f;
  }

  const int wave = t >> 6, lane = t & 63;
  const int half = lane >> 5, l31 = lane & 31;
  const int rt0 = (wave >> 1) << 1;    // row-tile pair base: 0 or 2
  const int ct0 = (wave & 1) << 1;     // col-tile pair base: 0 or 2
  const int col0 = ct0 * 32 + l31, col1 = col0 + 32;

  for (int c = 0; c < NCH_; ++c) {
    const int nb = n0 + c * CHUNK_;
    __syncthreads();   // init done (c==0) / previous stage-B readers done (c>0)

    // ---------- stage A: K=16 single MFMA per 32x32 tile, A from global x ----------
    {
      bf16x8 bf0 = *(const bf16x8*)&sW1T[col0][half * 8];
      bf16x8 bf1 = *(const bf16x8*)&sW1T[col1][half * 8];
      const float bv0 = sB1[col0], bv1 = sB1[col1];
      #pragma unroll
      for (int dr = 0; dr < 2; ++dr) {
        const int rt = rt0 + dr;
        bf16x8 af = load_cvt8(&x[((size_t)b * N_ + nb + rt * 32 + l31) * DIM_ + half * 8]);
        floatx16 a0, a1;
        #pragma unroll
        for (int r = 0; r < 16; ++r) { a0[r] = bv0; a1[r] = bv1; }
        a0 = __builtin_amdgcn_mfma_f32_32x32x16_bf16(af, bf0, a0, 0, 0, 0);
        a1 = __builtin_amdgcn_mfma_f32_32x32x16_bf16(af, bf1, a1, 0, 0, 0);
        #pragma unroll
        for (int r = 0; r < 16; ++r) {
          const int row = rt * 32 + (r & 3) + ((r >> 2) << 3) + (half << 2);
          sH1[row][col0] = (__bf16)fmaxf(a0[r], 0.f);
          sH1[row][col1] = (__bf16)fmaxf(a1[r], 0.f);
        }
      }
    }
    __syncthreads();   // sH1 ready

    // ---------- stage B: K=128, 2x2 register blocking per wave ----------
    {
      floatx16 c00, c01, c10, c11;
      const float bv0 = sB2[col0], bv1 = sB2[col1];
      #pragma unroll
      for (int r = 0; r < 16; ++r) { c00[r] = bv0; c01[r] = bv1; c10[r] = bv0; c11[r] = bv1; }
      #pragma unroll
      for (int ks = 0; ks < 8; ++ks) {
        const int ko = ks * 16 + half * 8;
        bf16x8 A0 = *(const bf16x8*)&sH1[rt0 * 32      + l31][ko];
        bf16x8 A1 = *(const bf16x8*)&sH1[rt0 * 32 + 32 + l31][ko];
        bf16x8 B0 = *(const bf16x8*)&sW2T[col0][ko];
        bf16x8 B1 = *(const bf16x8*)&sW2T[col1][ko];
        c00 = __builtin_amdgcn_mfma_f32_32x32x16_bf16(A0, B0, c00, 0, 0, 0);
        c01 = __builtin_amdgcn_mfma_f32_32x32x16_bf16(A0, B1, c01, 0, 0, 0);
        c10 = __builtin_amdgcn_mfma_f32_32x32x16_bf16(A1, B0, c10, 0, 0, 0);
        c11 = __builtin_amdgcn_mfma_f32_32x32x16_bf16(A1, B1, c11, 0, 0, 0);
      }
      // relu + adjacency mask + row-sum (C layout: col=lane&31, row=(r&3)+8*(r>>2)+4*half)
      float p0 = 0.f, p1 = 0.f;
      #pragma unroll
      for (int g = 0; g < 4; ++g) {
        const float4 m0 = *(const float4*)&adj[nb + rt0 * 32      + (half << 2) + (g << 3)];
        const float4 m1 = *(const float4*)&adj[nb + rt0 * 32 + 32 + (half << 2) + (g << 3)];
        p0 += fmaxf(c00[4*g+0], 0.f) * m0.x + fmaxf(c00[4*g+1], 0.f) * m0.y
            + fmaxf(c00[4*g+2], 0.f) * m0.z + fmaxf(c00[4*g+3], 0.f) * m0.w;
        p0 += fmaxf(c10[4*g+0], 0.f) * m1.x + fmaxf(c10[4*g+1], 0.f) * m1.y
            + fmaxf(c10[4*g+2], 0.f) * m1.z + fmaxf(c10[4*g+3], 0.f) * m1.w;
        p1 += fmaxf(c01[4*g+0], 0.f) * m0.x + fmaxf(c01[4*g+1], 0.f) * m0.y
            + fmaxf(c01[4*g+2], 0.f) * m0.z + fmaxf(c01[4*g+3], 0.f) * m0.w;
        p1 += fmaxf(c11[4*g+0], 0.f) * m1.x + fmaxf(c11[4*g+1], 0.f) * m1.y
            + fmaxf(c11[4*g+2], 0.f) * m1.z + fmaxf(c11[4*g+3], 0.f) * m1.w;
      }
      atomicAdd(&sAcc[col0], p0);
      atomicAdd(&sAcc[col1], p1);
    }
  }
  __syncthreads();
  if (t < HID_) atomicAdd(&accg[b * HID_ + t], sAcc[t]);
}

// h3 = relu(acc@W_e2n+b); h4 = relu(h3@W_n2n+b); out = [x[:,i,:]|h4]@W_out+b_out
__global__ void tail_kernel(
    const float* __restrict__ x, const float* __restrict__ acc,
    const float* __restrict__ W3, const float* __restrict__ b3,
    const float* __restrict__ W4, const float* __restrict__ b4,
    const float* __restrict__ W5, const float* __restrict__ b5,
    const int* __restrict__ ip, float* __restrict__ out)
{
  const int b = blockIdx.x, t = threadIdx.x;   // 128 threads
  __shared__ float s0[HID_], s1[HID_], s2[HID_], se[DIM_];
  const int ii = __ldg(ip);
  if (t < DIM_) se[t] = x[((size_t)b * N_ + ii) * DIM_ + t];
  s0[t] = acc[b * HID_ + t];
  __syncthreads();
  float v = b3[t];
  for (int k = 0; k < HID_; ++k) v += s0[k] * W3[k * HID_ + t];
  s1[t] = fmaxf(v, 0.f);
  __syncthreads();
  float w = b4[t];
  for (int k = 0; k < HID_; ++k) w += s1[k] * W4[k * HID_ + t];
  s2[t] = fmaxf(w, 0.f);
  __syncthreads();
  if (t < DIM_) {
    float o = b5[t];
    #pragma unroll
    for (int k = 0; k < DIM_; ++k) o += se[k] * W5[k * DIM_ + t];
    for (int k = 0; k < HID_; ++k) o += s2[k] * W5[(DIM_ + k) * DIM_ + t];
    out[b * DIM_ + t] = o;
  }
}

extern "C" void kernel_launch(void* const* d_in, const int* in_sizes, int n_in,
                              void* d_out, int out_size, void* d_ws, size_t ws_size,
                              hipStream_t stream) {
  const float* x   = (const float*)d_in[0];
  const float* adj = (const float*)d_in[1];
  const float* W1  = (const float*)d_in[2];   // W_n2e [32,128]
  const float* b1  = (const float*)d_in[3];
  const float* W2  = (const float*)d_in[4];   // W_e2e [128,128]
  const float* b2  = (const float*)d_in[5];
  const float* W3  = (const float*)d_in[6];   // W_e2n
  const float* b3  = (const float*)d_in[7];
  const float* W4  = (const float*)d_in[8];   // W_n2n
  const float* b4  = (const float*)d_in[9];
  const float* W5  = (const float*)d_in[10];  // W_out [144,16]
  const float* b5  = (const float*)d_in[11];
  const int*   ip  = (const int*)d_in[12];
  float* out  = (float*)d_out;
  float* accg = (float*)d_ws;                 // [B, HID] fp32 accumulator

  hipMemsetAsync(accg, 0, B_ * HID_ * sizeof(float), stream);
  edge_kernel<<<dim3(N_ / ROWS_, B_), 256, 0, stream>>>(x, adj, W1, b1, W2, b2, ip, accg);
  tail_kernel<<<B_, HID_, 0, stream>>>(x, accg, W3, b3, W4, b4, W5, b5, ip, out);
}